// Round 5
// baseline (85.882 us; speedup 1.0000x reference)
//
#include <hip/hip_runtime.h>
#include <stdint.h>

// Problem constants
#define NS 128   // n_seq (contraction dim, mean divisor)
#define NR 256   // S residues
#define CM 256   // c_m
#define CH 32    // c_hidden
#define CZ 128   // c_z

typedef __attribute__((ext_vector_type(4))) float f32x4;
typedef __attribute__((ext_vector_type(8))) short bf16x8;   // 8 bf16 in 4 VGPRs
typedef __attribute__((ext_vector_type(4))) unsigned short u16x4;

__device__ __forceinline__ unsigned short bf16rne(float x) {
    unsigned int u = __builtin_bit_cast(unsigned int, x);
    return (unsigned short)((u + 0x7FFFu + ((u >> 16) & 1u)) >> 16);
}

// ---------------------------------------------------------------------------
// k0: repack Wa|Wb and Wo into MFMA B-fragment-major layouts (bf16).
// Wab_f[n 0..3][ks 0..7][lane][e] = W[c = ks*32 + (lane>>4)*8 + e][k = n*16 + (lane&15)]
// Wo_f [c 0..31][kt 0..7][lane][e] = Wo[(c*32 + d)*CZ + k], d=(lane>>4)*8+e, k=kt*16+(lane&15)
// ---------------------------------------------------------------------------
__global__ __launch_bounds__(256) void k_wrepack(const float* __restrict__ Wa,
                                                 const float* __restrict__ Wb,
                                                 const float* __restrict__ Wo,
                                                 unsigned short* __restrict__ Wab_f,
                                                 unsigned short* __restrict__ Wo_f) {
    int idx = blockIdx.x * 256 + threadIdx.x;
    int l = idx & 63;
    int lo = l & 15, hi = l >> 4;
    if (idx < 2048) {
        int ks = (idx >> 6) & 7;
        int n = idx >> 9;
        int k = n * 16 + lo;
        bf16x8 v;
#pragma unroll
        for (int e = 0; e < 8; ++e) {
            int c = ks * 32 + hi * 8 + e;
            float wv = (k < CH) ? Wa[c * CH + k] : Wb[c * CH + (k - CH)];
            v[e] = (short)bf16rne(wv);
        }
        *reinterpret_cast<bf16x8*>(Wab_f + (size_t)idx * 8) = v;
    } else if (idx < 2048 + 16384) {
        int t = idx - 2048;
        int kt = (t >> 6) & 7;
        int c = t >> 9;
        int k = kt * 16 + lo;
        bf16x8 v;
#pragma unroll
        for (int e = 0; e < 8; ++e) {
            int d = hi * 8 + e;
            v[e] = (short)bf16rne(Wo[(size_t)(c * 32 + d) * CZ + k]);
        }
        *reinterpret_cast<bf16x8*>(Wo_f + (size_t)t * 8) = v;
    }
}

// ---------------------------------------------------------------------------
// k1: LayerNorm + dual projection via MFMA.
// ---------------------------------------------------------------------------
__global__ __launch_bounds__(256) void k_lnproj(const float* __restrict__ m,
                                                const float* __restrict__ lnw,
                                                const float* __restrict__ lnb,
                                                const float* __restrict__ ba,
                                                const float* __restrict__ bb,
                                                const unsigned short* __restrict__ Wab_f,
                                                unsigned short* __restrict__ a_n,
                                                unsigned short* __restrict__ b_n) {
    __shared__ unsigned short mn_lds[64 * 256];   // 32 KB, rows of 512 B, XOR-swizzled
    const int tid = threadIdx.x, l = tid & 63, w = tid >> 6;
    const int lo = l & 15, hi = l >> 4;
    const int R0 = blockIdx.x * 64;

    float4 wv = *reinterpret_cast<const float4*>(lnw + l * 4);
    float4 bv = *reinterpret_cast<const float4*>(lnb + l * 4);

    for (int t = 0; t < 16; ++t) {
        int row = w * 16 + t;
        int gr = R0 + row;
        float4 x = *reinterpret_cast<const float4*>(m + (size_t)gr * CM + l * 4);
        float sum = x.x + x.y + x.z + x.w;
        float sq = x.x * x.x + x.y * x.y + x.z * x.z + x.w * x.w;
#pragma unroll
        for (int off = 32; off; off >>= 1) {
            sum += __shfl_xor(sum, off);
            sq  += __shfl_xor(sq, off);
        }
        float mu = sum * (1.f / CM);
        float rstd = rsqrtf(sq * (1.f / CM) - mu * mu + 1e-5f);
        u16x4 pk;
        pk[0] = bf16rne((x.x - mu) * rstd * wv.x + bv.x);
        pk[1] = bf16rne((x.y - mu) * rstd * wv.y + bv.y);
        pk[2] = bf16rne((x.z - mu) * rstd * wv.z + bv.z);
        pk[3] = bf16rne((x.w - mu) * rstd * wv.w + bv.w);
        int byte = row * 512 + l * 8;
        byte ^= (row & 7) << 4;
        *reinterpret_cast<u16x4*>(reinterpret_cast<char*>(mn_lds) + byte) = pk;
    }

    // Projection: per wave, [16 rows x 256] @ [256 x 64]  (no barrier: stripe is wave-private)
    f32x4 acc[4];
#pragma unroll
    for (int n = 0; n < 4; ++n) acc[n] = (f32x4){0.f, 0.f, 0.f, 0.f};
    const int arow = w * 16 + lo;
#pragma unroll
    for (int ks = 0; ks < 8; ++ks) {
        int byte = arow * 512 + ks * 64 + hi * 16;
        byte ^= (arow & 7) << 4;
        bf16x8 afrag = *reinterpret_cast<const bf16x8*>(reinterpret_cast<const char*>(mn_lds) + byte);
#pragma unroll
        for (int n = 0; n < 4; ++n) {
            bf16x8 bfrag = *reinterpret_cast<const bf16x8*>(Wab_f + (size_t)((n * 8 + ks) * 64 + l) * 8);
            acc[n] = __builtin_amdgcn_mfma_f32_16x16x32_bf16(afrag, bfrag, acc[n], 0, 0, 0);
        }
    }
#pragma unroll
    for (int n = 0; n < 4; ++n) {
        int k = n * 16 + lo;
        float bias = (k < CH) ? ba[k] : bb[k - CH];
#pragma unroll
        for (int r = 0; r < 4; ++r) {
            int gr = R0 + w * 16 + hi * 4 + r;
            unsigned short hv = bf16rne(acc[n][r] + bias);
            if (k < CH) a_n[(size_t)gr * CH + k] = hv;
            else        b_n[(size_t)gr * CH + (k - CH)] = hv;
        }
    }
}

// ---------------------------------------------------------------------------
// k2: repack a_n/b_n (bf16 bits) into fragment-major a_f/b_f (pure bit moves).
// ---------------------------------------------------------------------------
__global__ __launch_bounds__(256) void k_abrepack(const unsigned short* __restrict__ a_n,
                                                  const unsigned short* __restrict__ b_n,
                                                  unsigned short* __restrict__ a_f,
                                                  unsigned short* __restrict__ b_f) {
    int idx = blockIdx.x * 256 + threadIdx.x;
    int lo = idx & 15, hi = (idx >> 4) & 3;
    if (idx < 131072) {
        int ks = (idx >> 6) & 3, it = (idx >> 8) & 15, c = idx >> 12;
        int i = it * 16 + lo;
        bf16x8 v;
#pragma unroll
        for (int e = 0; e < 8; ++e) {
            int s = ks * 32 + hi * 8 + e;
            v[e] = (short)a_n[((size_t)s * NR + i) * CH + c];
        }
        *reinterpret_cast<bf16x8*>(a_f + (size_t)idx * 8) = v;
    } else {
        int t = idx - 131072;
        int ks = (t >> 6) & 3, tt = t >> 8;
        int j = tt >> 1, d = (tt & 1) * 16 + lo;
        bf16x8 v;
#pragma unroll
        for (int e = 0; e < 8; ++e) {
            int s = ks * 32 + hi * 8 + e;
            v[e] = (short)b_n[((size_t)s * NR + j) * CH + d];
        }
        *reinterpret_cast<bf16x8*>(b_f + (size_t)t * 8) = v;
    }
}

// ---------------------------------------------------------------------------
// k3: fused outer-product-mean + Wo projection.
// Grid 512 blocks (bi 0..15, bj 0..31), 512 thr (8 waves). Block tile 16i x 8j;
// wave w owns j = bj*8 + w (J=1). b-slice per wave = 8 frags = 32 VGPR ->
// fully register-resident AND <=128 VGPR total => 4 waves/SIMD (16 waves/CU).
// af/wof fragment loads are identical across the 8 waves (L1-hot).
// Per c: stage A (8 MFMA, swapped operands) -> swizzled O_lds (wave-private
// 64B stripe, zero barriers) -> stage B (8 MFMA vs Wo).
// ---------------------------------------------------------------------------
__global__ __launch_bounds__(512, 4) void k_outer(const unsigned short* __restrict__ a_f,
                                                  const unsigned short* __restrict__ b_f,
                                                  const unsigned short* __restrict__ Wo_f,
                                                  const float* __restrict__ bo,
                                                  float* __restrict__ out) {
    __shared__ unsigned short O_lds[16 * 256];   // 8 KB: 16 i-rows x 256 cols, XOR-swizzled
    const int tid = threadIdx.x, l = tid & 63, w = tid >> 6;   // w in 0..7
    const int lo = l & 15, hi = l >> 4;
    const int bi = blockIdx.x >> 5, bj = blockIdx.x & 31;

    // This wave's entire b-slice (j = bj*8 + w): 8 fragments = 32 VGPR.
    bf16x8 bfr[2][4];
#pragma unroll
    for (int q = 0; q < 2; ++q)
#pragma unroll
        for (int ks = 0; ks < 4; ++ks) {
            int nt = bj * 16 + w * 2 + q;
            bfr[q][ks] = *reinterpret_cast<const bf16x8*>(b_f + (size_t)((nt * 4 + ks) * 64 + l) * 8);
        }

    f32x4 zacc[8];   // 32 VGPR
#pragma unroll
    for (int kt = 0; kt < 8; ++kt) zacc[kt] = (f32x4){0.f, 0.f, 0.f, 0.f};

#pragma unroll 2
    for (int c = 0; c < 32; ++c) {
        // af: 4 frags, identical across the 8 waves (L1-hot after first wave)
        bf16x8 af[4];
#pragma unroll
        for (int ks = 0; ks < 4; ++ks)
            af[ks] = *reinterpret_cast<const bf16x8*>(a_f + (size_t)(((c * 16 + bi) * 4 + ks) * 64 + l) * 8);

        // Stage A: O^T fragments (swapped operands: lane holds 4 consecutive d) -> LDS
#pragma unroll
        for (int q = 0; q < 2; ++q) {
            f32x4 o = (f32x4){0.f, 0.f, 0.f, 0.f};
#pragma unroll
            for (int ks = 0; ks < 4; ++ks)
                o = __builtin_amdgcn_mfma_f32_16x16x32_bf16(bfr[q][ks], af[ks], o, 0, 0, 0);
            u16x4 pk;
            pk[0] = bf16rne(o[0]); pk[1] = bf16rne(o[1]);
            pk[2] = bf16rne(o[2]); pk[3] = bf16rne(o[3]);
            // O_lds[i = lo][col = w*32 + q*16 + hi*4 + r], byte = i*512 + col*2
            int byte = (lo << 9) + w * 64 + q * 32 + (hi << 3);
            byte ^= (lo & 7) << 4;
            *reinterpret_cast<u16x4*>(reinterpret_cast<char*>(O_lds) + byte) = pk;
        }

        // Stage B: z += O_c @ Wo_c  (read own stripe: row i=lo, d = hi*8..hi*8+7)
        int rbyte = (lo << 9) + w * 64 + (hi << 4);
        rbyte ^= (lo & 7) << 4;
        bf16x8 ofrag = *reinterpret_cast<const bf16x8*>(reinterpret_cast<const char*>(O_lds) + rbyte);
#pragma unroll
        for (int h = 0; h < 2; ++h) {
            bf16x8 wof[4];
#pragma unroll
            for (int t = 0; t < 4; ++t)
                wof[t] = *reinterpret_cast<const bf16x8*>(Wo_f + (size_t)((c * 8 + h * 4 + t) * 64 + l) * 8);
#pragma unroll
            for (int t = 0; t < 4; ++t)
                zacc[h * 4 + t] = __builtin_amdgcn_mfma_f32_16x16x32_bf16(ofrag, wof[t], zacc[h * 4 + t], 0, 0, 0);
        }
    }

    // Epilogue: /n_seq + bo
    const int j = bj * 8 + w;
#pragma unroll
    for (int kt = 0; kt < 8; ++kt) {
        int k = kt * 16 + lo;
        float bok = bo[k];
#pragma unroll
        for (int r = 0; r < 4; ++r) {
            int i = bi * 16 + hi * 4 + r;
            out[((size_t)i * NR + j) * CZ + k] = zacc[kt][r] * (1.f / NS) + bok;
        }
    }
}

// ---------------------------------------------------------------------------
extern "C" void kernel_launch(void* const* d_in, const int* in_sizes, int n_in,
                              void* d_out, int out_size, void* d_ws, size_t ws_size,
                              hipStream_t stream) {
    const float* m   = (const float*)d_in[0];
    const float* lnw = (const float*)d_in[1];
    const float* lnb = (const float*)d_in[2];
    const float* Wa  = (const float*)d_in[3];
    const float* ba  = (const float*)d_in[4];
    const float* Wb  = (const float*)d_in[5];
    const float* bb  = (const float*)d_in[6];
    const float* Wo  = (const float*)d_in[7];
    const float* bo  = (const float*)d_in[8];
    float* out = (float*)d_out;

    // ws layout (ushort units): a_n | b_n | a_f | b_f | Wab_f | Wo_f
    unsigned short* ws    = (unsigned short*)d_ws;
    unsigned short* a_n   = ws;
    unsigned short* b_n   = ws + 1048576;
    unsigned short* a_f   = ws + 2097152;
    unsigned short* b_f   = ws + 3145728;
    unsigned short* Wab_f = ws + 4194304;
    unsigned short* Wo_f  = ws + 4210688;
    const size_t WS_NEEDED = (size_t)(4210688 + 131072) * 2;
    if (ws_size < WS_NEEDED) return;   // diagnosable: output stays poisoned

    k_wrepack<<<72, 256, 0, stream>>>(Wa, Wb, Wo, Wab_f, Wo_f);
    k_lnproj<<<512, 256, 0, stream>>>(m, lnw, lnb, ba, bb, Wab_f, a_n, b_n);
    k_abrepack<<<1024, 256, 0, stream>>>(a_n, b_n, a_f, b_f);
    k_outer<<<512, 512, 0, stream>>>(a_f, b_f, Wo_f, bo, out);
}

// Round 6
// 69.951 us; speedup vs baseline: 1.2277x; 1.2277x over previous
//
#include <hip/hip_runtime.h>
#include <stdint.h>

// Problem constants
#define NS 128   // n_seq (contraction dim, mean divisor)
#define NR 256   // S residues
#define CM 256   // c_m
#define CH 32    // c_hidden
#define CZ 128   // c_z

typedef __attribute__((ext_vector_type(4))) float f32x4;
typedef __attribute__((ext_vector_type(8))) short bf16x8;   // 8 bf16 in 4 VGPRs
typedef __attribute__((ext_vector_type(4))) unsigned short u16x4;

__device__ __forceinline__ unsigned short bf16rne(float x) {
    unsigned int u = __builtin_bit_cast(unsigned int, x);
    return (unsigned short)((u + 0x7FFFu + ((u >> 16) & 1u)) >> 16);
}

// ---------------------------------------------------------------------------
// k0: repack Wa|Wb and Wo into MFMA B-fragment-major layouts (bf16).
// ---------------------------------------------------------------------------
__global__ __launch_bounds__(256) void k_wrepack(const float* __restrict__ Wa,
                                                 const float* __restrict__ Wb,
                                                 const float* __restrict__ Wo,
                                                 unsigned short* __restrict__ Wab_f,
                                                 unsigned short* __restrict__ Wo_f) {
    int idx = blockIdx.x * 256 + threadIdx.x;
    int l = idx & 63;
    int lo = l & 15, hi = l >> 4;
    if (idx < 2048) {
        int ks = (idx >> 6) & 7;
        int n = idx >> 9;
        int k = n * 16 + lo;
        bf16x8 v;
#pragma unroll
        for (int e = 0; e < 8; ++e) {
            int c = ks * 32 + hi * 8 + e;
            float wv = (k < CH) ? Wa[c * CH + k] : Wb[c * CH + (k - CH)];
            v[e] = (short)bf16rne(wv);
        }
        *reinterpret_cast<bf16x8*>(Wab_f + (size_t)idx * 8) = v;
    } else if (idx < 2048 + 16384) {
        int t = idx - 2048;
        int kt = (t >> 6) & 7;
        int c = t >> 9;
        int k = kt * 16 + lo;
        bf16x8 v;
#pragma unroll
        for (int e = 0; e < 8; ++e) {
            int d = hi * 8 + e;
            v[e] = (short)bf16rne(Wo[(size_t)(c * 32 + d) * CZ + k]);
        }
        *reinterpret_cast<bf16x8*>(Wo_f + (size_t)t * 8) = v;
    }
}

// ---------------------------------------------------------------------------
// k1: LayerNorm + dual projection via MFMA.
// ---------------------------------------------------------------------------
__global__ __launch_bounds__(256) void k_lnproj(const float* __restrict__ m,
                                                const float* __restrict__ lnw,
                                                const float* __restrict__ lnb,
                                                const float* __restrict__ ba,
                                                const float* __restrict__ bb,
                                                const unsigned short* __restrict__ Wab_f,
                                                unsigned short* __restrict__ a_n,
                                                unsigned short* __restrict__ b_n) {
    __shared__ unsigned short mn_lds[64 * 256];   // 32 KB, rows of 512 B, XOR-swizzled
    const int tid = threadIdx.x, l = tid & 63, w = tid >> 6;
    const int lo = l & 15, hi = l >> 4;
    const int R0 = blockIdx.x * 64;

    float4 wv = *reinterpret_cast<const float4*>(lnw + l * 4);
    float4 bv = *reinterpret_cast<const float4*>(lnb + l * 4);

    for (int t = 0; t < 16; ++t) {
        int row = w * 16 + t;
        int gr = R0 + row;
        float4 x = *reinterpret_cast<const float4*>(m + (size_t)gr * CM + l * 4);
        float sum = x.x + x.y + x.z + x.w;
        float sq = x.x * x.x + x.y * x.y + x.z * x.z + x.w * x.w;
#pragma unroll
        for (int off = 32; off; off >>= 1) {
            sum += __shfl_xor(sum, off);
            sq  += __shfl_xor(sq, off);
        }
        float mu = sum * (1.f / CM);
        float rstd = rsqrtf(sq * (1.f / CM) - mu * mu + 1e-5f);
        u16x4 pk;
        pk[0] = bf16rne((x.x - mu) * rstd * wv.x + bv.x);
        pk[1] = bf16rne((x.y - mu) * rstd * wv.y + bv.y);
        pk[2] = bf16rne((x.z - mu) * rstd * wv.z + bv.z);
        pk[3] = bf16rne((x.w - mu) * rstd * wv.w + bv.w);
        int byte = row * 512 + l * 8;
        byte ^= (row & 7) << 4;
        *reinterpret_cast<u16x4*>(reinterpret_cast<char*>(mn_lds) + byte) = pk;
    }

    // Projection: per wave, [16 rows x 256] @ [256 x 64]  (no barrier: stripe is wave-private)
    f32x4 acc[4];
#pragma unroll
    for (int n = 0; n < 4; ++n) acc[n] = (f32x4){0.f, 0.f, 0.f, 0.f};
    const int arow = w * 16 + lo;
#pragma unroll
    for (int ks = 0; ks < 8; ++ks) {
        int byte = arow * 512 + ks * 64 + hi * 16;
        byte ^= (arow & 7) << 4;
        bf16x8 afrag = *reinterpret_cast<const bf16x8*>(reinterpret_cast<const char*>(mn_lds) + byte);
#pragma unroll
        for (int n = 0; n < 4; ++n) {
            bf16x8 bfrag = *reinterpret_cast<const bf16x8*>(Wab_f + (size_t)((n * 8 + ks) * 64 + l) * 8);
            acc[n] = __builtin_amdgcn_mfma_f32_16x16x32_bf16(afrag, bfrag, acc[n], 0, 0, 0);
        }
    }
#pragma unroll
    for (int n = 0; n < 4; ++n) {
        int k = n * 16 + lo;
        float bias = (k < CH) ? ba[k] : bb[k - CH];
#pragma unroll
        for (int r = 0; r < 4; ++r) {
            int gr = R0 + w * 16 + hi * 4 + r;
            unsigned short hv = bf16rne(acc[n][r] + bias);
            if (k < CH) a_n[(size_t)gr * CH + k] = hv;
            else        b_n[(size_t)gr * CH + (k - CH)] = hv;
        }
    }
}

// ---------------------------------------------------------------------------
// k2: repack a_n/b_n (bf16 bits) into fragment-major a_f/b_f (pure bit moves).
// ---------------------------------------------------------------------------
__global__ __launch_bounds__(256) void k_abrepack(const unsigned short* __restrict__ a_n,
                                                  const unsigned short* __restrict__ b_n,
                                                  unsigned short* __restrict__ a_f,
                                                  unsigned short* __restrict__ b_f) {
    int idx = blockIdx.x * 256 + threadIdx.x;
    int lo = idx & 15, hi = (idx >> 4) & 3;
    if (idx < 131072) {
        int ks = (idx >> 6) & 3, it = (idx >> 8) & 15, c = idx >> 12;
        int i = it * 16 + lo;
        bf16x8 v;
#pragma unroll
        for (int e = 0; e < 8; ++e) {
            int s = ks * 32 + hi * 8 + e;
            v[e] = (short)a_n[((size_t)s * NR + i) * CH + c];
        }
        *reinterpret_cast<bf16x8*>(a_f + (size_t)idx * 8) = v;
    } else {
        int t = idx - 131072;
        int ks = (t >> 6) & 3, tt = t >> 8;
        int j = tt >> 1, d = (tt & 1) * 16 + lo;
        bf16x8 v;
#pragma unroll
        for (int e = 0; e < 8; ++e) {
            int s = ks * 32 + hi * 8 + e;
            v[e] = (short)b_n[((size_t)s * NR + j) * CH + d];
        }
        *reinterpret_cast<bf16x8*>(b_f + (size_t)t * 8) = v;
    }
}

// ---------------------------------------------------------------------------
// k3: fused outer-product-mean + Wo projection, software-pipelined, with
// b-fragments FORCED register-resident via asm pins (rule #17): the compiler
// has sunk these loads into the c-loop in every prior round (VGPR 48-96),
// re-streaming 1.9-2.7 GB from L1/L2 at the ~40 TB/s fill ceiling.
// Grid 512 blocks (bi 0..15, bj 0..31), 256 thr (4 waves). Block tile 16i x 8j;
// wave w owns j = bj*8 + w*2 + {0,1} (J=2). Zero barriers (wave-private O stripe).
// ---------------------------------------------------------------------------
__global__ __launch_bounds__(256, 2) void k_outer(const unsigned short* __restrict__ a_f,
                                                  const unsigned short* __restrict__ b_f,
                                                  const unsigned short* __restrict__ Wo_f,
                                                  const float* __restrict__ bo,
                                                  float* __restrict__ out) {
    __shared__ unsigned short O_lds[16 * 256];   // 8 KB: 16 i-rows x 256 cols, XOR-swizzled
    const int tid = threadIdx.x, l = tid & 63, w = tid >> 6;   // w in 0..3
    const int lo = l & 15, hi = l >> 4;
    const int bi = blockIdx.x >> 5, bj = blockIdx.x & 31;

    // Preload this wave's 16 b-fragments (cols [bj*256 + w*64, +64)) = 64 VGPR
    bf16x8 bfr[4][4];
#pragma unroll
    for (int q = 0; q < 4; ++q)
#pragma unroll
        for (int ks = 0; ks < 4; ++ks) {
            int nt = bj * 16 + w * 4 + q;
            bfr[q][ks] = *reinterpret_cast<const bf16x8*>(b_f + (size_t)((nt * 4 + ks) * 64 + l) * 8);
        }
    // PIN: force bfr to stay in VGPRs across the c-loop (compiler may not
    // rematerialize a value an asm could have modified).
#pragma unroll
    for (int q = 0; q < 4; ++q)
#pragma unroll
        for (int ks = 0; ks < 4; ++ks)
            asm volatile("" : "+v"(bfr[q][ks]));

    f32x4 zacc[2][8];
#pragma unroll
    for (int jj = 0; jj < 2; ++jj)
#pragma unroll
        for (int kt = 0; kt < 8; ++kt)
            zacc[jj][kt] = (f32x4){0.f, 0.f, 0.f, 0.f};

    // Prologue: af for c=0
    bf16x8 af[4], afn[4];
#pragma unroll
    for (int ks = 0; ks < 4; ++ks)
        af[ks] = *reinterpret_cast<const bf16x8*>(a_f + (size_t)(((0 * 16 + bi) * 4 + ks) * 64 + l) * 8);

#pragma unroll 2
    for (int c = 0; c < 32; ++c) {
        int cn = (c + 1) & 31;   // wrap: last prefetch harmless
        // Early-issue: wof for this c (consumed in stage B), af for next c
        bf16x8 wof[8];
#pragma unroll
        for (int kt = 0; kt < 8; ++kt)
            wof[kt] = *reinterpret_cast<const bf16x8*>(Wo_f + (size_t)((c * 8 + kt) * 64 + l) * 8);
#pragma unroll
        for (int ks = 0; ks < 4; ++ks)
            afn[ks] = *reinterpret_cast<const bf16x8*>(a_f + (size_t)(((cn * 16 + bi) * 4 + ks) * 64 + l) * 8);

        // Stage A: O^T fragments (swapped operands) -> swizzled LDS (ds_write_b64)
#pragma unroll
        for (int q = 0; q < 4; ++q) {
            f32x4 o = (f32x4){0.f, 0.f, 0.f, 0.f};
#pragma unroll
            for (int ks = 0; ks < 4; ++ks)
                o = __builtin_amdgcn_mfma_f32_16x16x32_bf16(bfr[q][ks], af[ks], o, 0, 0, 0);
            u16x4 pk;
            pk[0] = bf16rne(o[0]); pk[1] = bf16rne(o[1]);
            pk[2] = bf16rne(o[2]); pk[3] = bf16rne(o[3]);
            // O_lds[i = lo][col = (w*4+q)*16 + hi*4 + r], byte = i*512 + col*2
            int byte = (lo << 9) + (w * 4 + q) * 32 + (hi << 3);
            byte ^= (lo & 7) << 4;
            *reinterpret_cast<u16x4*>(reinterpret_cast<char*>(O_lds) + byte) = pk;
        }

        // Stage B: z += O_c @ Wo_c   (wave reads only its own O stripe: no barrier)
#pragma unroll
        for (int jj = 0; jj < 2; ++jj) {
            int rbyte = (lo << 9) + w * 128 + jj * 64 + (hi << 4);
            rbyte ^= (lo & 7) << 4;
            bf16x8 ofrag = *reinterpret_cast<const bf16x8*>(reinterpret_cast<const char*>(O_lds) + rbyte);
#pragma unroll
            for (int kt = 0; kt < 8; ++kt)
                zacc[jj][kt] = __builtin_amdgcn_mfma_f32_16x16x32_bf16(ofrag, wof[kt], zacc[jj][kt], 0, 0, 0);
        }

        // Rotate prefetch buffer (SSA-renamed away under unroll 2)
#pragma unroll
        for (int ks = 0; ks < 4; ++ks) af[ks] = afn[ks];
    }

    // Epilogue: /n_seq + bo
#pragma unroll
    for (int jj = 0; jj < 2; ++jj) {
        int j = bj * 8 + w * 2 + jj;
#pragma unroll
        for (int kt = 0; kt < 8; ++kt) {
            int k = kt * 16 + lo;
            float bok = bo[k];
#pragma unroll
            for (int r = 0; r < 4; ++r) {
                int i = bi * 16 + hi * 4 + r;
                out[((size_t)i * NR + j) * CZ + k] = zacc[jj][kt][r] * (1.f / NS) + bok;
            }
        }
    }
}

// ---------------------------------------------------------------------------
extern "C" void kernel_launch(void* const* d_in, const int* in_sizes, int n_in,
                              void* d_out, int out_size, void* d_ws, size_t ws_size,
                              hipStream_t stream) {
    const float* m   = (const float*)d_in[0];
    const float* lnw = (const float*)d_in[1];
    const float* lnb = (const float*)d_in[2];
    const float* Wa  = (const float*)d_in[3];
    const float* ba  = (const float*)d_in[4];
    const float* Wb  = (const float*)d_in[5];
    const float* bb  = (const float*)d_in[6];
    const float* Wo  = (const float*)d_in[7];
    const float* bo  = (const float*)d_in[8];
    float* out = (float*)d_out;

    // ws layout (ushort units): a_n | b_n | a_f | b_f | Wab_f | Wo_f
    unsigned short* ws    = (unsigned short*)d_ws;
    unsigned short* a_n   = ws;
    unsigned short* b_n   = ws + 1048576;
    unsigned short* a_f   = ws + 2097152;
    unsigned short* b_f   = ws + 3145728;
    unsigned short* Wab_f = ws + 4194304;
    unsigned short* Wo_f  = ws + 4210688;
    const size_t WS_NEEDED = (size_t)(4210688 + 131072) * 2;
    if (ws_size < WS_NEEDED) return;   // diagnosable: output stays poisoned

    k_wrepack<<<72, 256, 0, stream>>>(Wa, Wb, Wo, Wab_f, Wo_f);
    k_lnproj<<<512, 256, 0, stream>>>(m, lnw, lnb, ba, bb, Wab_f, a_n, b_n);
    k_abrepack<<<1024, 256, 0, stream>>>(a_n, b_n, a_f, b_f);
    k_outer<<<512, 256, 0, stream>>>(a_f, b_f, Wo_f, bo, out);
}

// Round 7
// 64.709 us; speedup vs baseline: 1.3272x; 1.0810x over previous
//
#include <hip/hip_runtime.h>
#include <stdint.h>

// Problem constants
#define NS 128   // n_seq (contraction dim, mean divisor)
#define NR 256   // S residues
#define CM 256   // c_m
#define CH 32    // c_hidden
#define CZ 128   // c_z

typedef __attribute__((ext_vector_type(4))) float f32x4;
typedef __attribute__((ext_vector_type(8))) short bf16x8;   // 8 bf16 in 4 VGPRs
typedef __attribute__((ext_vector_type(4))) unsigned short u16x4;

__device__ __forceinline__ unsigned short bf16rne(float x) {
    unsigned int u = __builtin_bit_cast(unsigned int, x);
    return (unsigned short)((u + 0x7FFFu + ((u >> 16) & 1u)) >> 16);
}

// ---------------------------------------------------------------------------
// k0: repack Wa|Wb and Wo into MFMA B-fragment-major layouts (bf16).
// ---------------------------------------------------------------------------
__global__ __launch_bounds__(256) void k_wrepack(const float* __restrict__ Wa,
                                                 const float* __restrict__ Wb,
                                                 const float* __restrict__ Wo,
                                                 unsigned short* __restrict__ Wab_f,
                                                 unsigned short* __restrict__ Wo_f) {
    int idx = blockIdx.x * 256 + threadIdx.x;
    int l = idx & 63;
    int lo = l & 15, hi = l >> 4;
    if (idx < 2048) {
        int ks = (idx >> 6) & 7;
        int n = idx >> 9;
        int k = n * 16 + lo;
        bf16x8 v;
#pragma unroll
        for (int e = 0; e < 8; ++e) {
            int c = ks * 32 + hi * 8 + e;
            float wv = (k < CH) ? Wa[c * CH + k] : Wb[c * CH + (k - CH)];
            v[e] = (short)bf16rne(wv);
        }
        *reinterpret_cast<bf16x8*>(Wab_f + (size_t)idx * 8) = v;
    } else if (idx < 2048 + 16384) {
        int t = idx - 2048;
        int kt = (t >> 6) & 7;
        int c = t >> 9;
        int k = kt * 16 + lo;
        bf16x8 v;
#pragma unroll
        for (int e = 0; e < 8; ++e) {
            int d = hi * 8 + e;
            v[e] = (short)bf16rne(Wo[(size_t)(c * 32 + d) * CZ + k]);
        }
        *reinterpret_cast<bf16x8*>(Wo_f + (size_t)t * 8) = v;
    }
}

// ---------------------------------------------------------------------------
// k1: LayerNorm + dual projection via MFMA.
// ---------------------------------------------------------------------------
__global__ __launch_bounds__(256) void k_lnproj(const float* __restrict__ m,
                                                const float* __restrict__ lnw,
                                                const float* __restrict__ lnb,
                                                const float* __restrict__ ba,
                                                const float* __restrict__ bb,
                                                const unsigned short* __restrict__ Wab_f,
                                                unsigned short* __restrict__ a_n,
                                                unsigned short* __restrict__ b_n) {
    __shared__ unsigned short mn_lds[64 * 256];   // 32 KB, rows of 512 B, XOR-swizzled
    const int tid = threadIdx.x, l = tid & 63, w = tid >> 6;
    const int lo = l & 15, hi = l >> 4;
    const int R0 = blockIdx.x * 64;

    float4 wv = *reinterpret_cast<const float4*>(lnw + l * 4);
    float4 bv = *reinterpret_cast<const float4*>(lnb + l * 4);

    for (int t = 0; t < 16; ++t) {
        int row = w * 16 + t;
        int gr = R0 + row;
        float4 x = *reinterpret_cast<const float4*>(m + (size_t)gr * CM + l * 4);
        float sum = x.x + x.y + x.z + x.w;
        float sq = x.x * x.x + x.y * x.y + x.z * x.z + x.w * x.w;
#pragma unroll
        for (int off = 32; off; off >>= 1) {
            sum += __shfl_xor(sum, off);
            sq  += __shfl_xor(sq, off);
        }
        float mu = sum * (1.f / CM);
        float rstd = rsqrtf(sq * (1.f / CM) - mu * mu + 1e-5f);
        u16x4 pk;
        pk[0] = bf16rne((x.x - mu) * rstd * wv.x + bv.x);
        pk[1] = bf16rne((x.y - mu) * rstd * wv.y + bv.y);
        pk[2] = bf16rne((x.z - mu) * rstd * wv.z + bv.z);
        pk[3] = bf16rne((x.w - mu) * rstd * wv.w + bv.w);
        int byte = row * 512 + l * 8;
        byte ^= (row & 7) << 4;
        *reinterpret_cast<u16x4*>(reinterpret_cast<char*>(mn_lds) + byte) = pk;
    }

    // Projection: per wave, [16 rows x 256] @ [256 x 64]  (no barrier: stripe is wave-private)
    f32x4 acc[4];
#pragma unroll
    for (int n = 0; n < 4; ++n) acc[n] = (f32x4){0.f, 0.f, 0.f, 0.f};
    const int arow = w * 16 + lo;
#pragma unroll
    for (int ks = 0; ks < 8; ++ks) {
        int byte = arow * 512 + ks * 64 + hi * 16;
        byte ^= (arow & 7) << 4;
        bf16x8 afrag = *reinterpret_cast<const bf16x8*>(reinterpret_cast<const char*>(mn_lds) + byte);
#pragma unroll
        for (int n = 0; n < 4; ++n) {
            bf16x8 bfrag = *reinterpret_cast<const bf16x8*>(Wab_f + (size_t)((n * 8 + ks) * 64 + l) * 8);
            acc[n] = __builtin_amdgcn_mfma_f32_16x16x32_bf16(afrag, bfrag, acc[n], 0, 0, 0);
        }
    }
#pragma unroll
    for (int n = 0; n < 4; ++n) {
        int k = n * 16 + lo;
        float bias = (k < CH) ? ba[k] : bb[k - CH];
#pragma unroll
        for (int r = 0; r < 4; ++r) {
            int gr = R0 + w * 16 + hi * 4 + r;
            unsigned short hv = bf16rne(acc[n][r] + bias);
            if (k < CH) a_n[(size_t)gr * CH + k] = hv;
            else        b_n[(size_t)gr * CH + (k - CH)] = hv;
        }
    }
}

// ---------------------------------------------------------------------------
// k2: repack a_n/b_n (bf16 bits) into fragment-major a_f/b_f (pure bit moves).
// ---------------------------------------------------------------------------
__global__ __launch_bounds__(256) void k_abrepack(const unsigned short* __restrict__ a_n,
                                                  const unsigned short* __restrict__ b_n,
                                                  unsigned short* __restrict__ a_f,
                                                  unsigned short* __restrict__ b_f) {
    int idx = blockIdx.x * 256 + threadIdx.x;
    int lo = idx & 15, hi = (idx >> 4) & 3;
    if (idx < 131072) {
        int ks = (idx >> 6) & 3, it = (idx >> 8) & 15, c = idx >> 12;
        int i = it * 16 + lo;
        bf16x8 v;
#pragma unroll
        for (int e = 0; e < 8; ++e) {
            int s = ks * 32 + hi * 8 + e;
            v[e] = (short)a_n[((size_t)s * NR + i) * CH + c];
        }
        *reinterpret_cast<bf16x8*>(a_f + (size_t)idx * 8) = v;
    } else {
        int t = idx - 131072;
        int ks = (t >> 6) & 3, tt = t >> 8;
        int j = tt >> 1, d = (tt & 1) * 16 + lo;
        bf16x8 v;
#pragma unroll
        for (int e = 0; e < 8; ++e) {
            int s = ks * 32 + hi * 8 + e;
            v[e] = (short)b_n[((size_t)s * NR + j) * CH + d];
        }
        *reinterpret_cast<bf16x8*>(b_f + (size_t)t * 8) = v;
    }
}

// ---------------------------------------------------------------------------
// k3: fused outer-product-mean + Wo projection, b-operand staged in LDS.
// Grid 512 blocks (bi 0..15, bj 0..31), 256 thr (4 waves). Block tile 16i x 8j;
// wave w owns j = bj*8 + w*2 + {0,1} (J=2).
// b-stripe (64 KB) staged to LDS ONCE per block -> per-c b reads hit the DS
// pipe (16x ds_read_b128/wave-c) while af+wof (12 KB/wave-c) use VMEM:
// operand fill is split across both pipes instead of all hitting L1 (~40 TB/s
// ceiling, the R2-R6 bottleneck). O_lds parity-double-buffered (no cross-c WAR).
// LDS = 64 + 16 KB = 80 KB -> exactly 2 blocks/CU. One barrier total.
// ---------------------------------------------------------------------------
__global__ __launch_bounds__(256, 2) void k_outer(const unsigned short* __restrict__ a_f,
                                                  const unsigned short* __restrict__ b_f,
                                                  const unsigned short* __restrict__ Wo_f,
                                                  const float* __restrict__ bo,
                                                  float* __restrict__ out) {
    __shared__ unsigned short b_lds[32768];        // 64 KB: block's b stripe, frag-major
    __shared__ unsigned short O_lds[2][4096];      // 2 x 8 KB: 16 i-rows x 512 B, swizzled
    const int tid = threadIdx.x, l = tid & 63, w = tid >> 6;   // w in 0..3
    const int lo = l & 15, hi = l >> 4;
    const int bi = blockIdx.x >> 5, bj = blockIdx.x & 31;

    // Stage b stripe: b_f slice for bj is contiguous (16 nt x 4 ks x 64 x 8 shorts).
    {
        const unsigned short* src = b_f + (size_t)bj * 32768;
#pragma unroll
        for (int it = 0; it < 16; ++it) {
            int off = it * 2048 + tid * 8;
            *reinterpret_cast<bf16x8*>(b_lds + off) =
                *reinterpret_cast<const bf16x8*>(src + off);
        }
    }
    __syncthreads();

    f32x4 zacc[2][8];
#pragma unroll
    for (int jj = 0; jj < 2; ++jj)
#pragma unroll
        for (int kt = 0; kt < 8; ++kt)
            zacc[jj][kt] = (f32x4){0.f, 0.f, 0.f, 0.f};

#pragma unroll 2
    for (int c = 0; c < 32; ++c) {
        // VMEM: wof (consumed in stage B, issued early) + af for this c
        bf16x8 wof[8];
#pragma unroll
        for (int kt = 0; kt < 8; ++kt)
            wof[kt] = *reinterpret_cast<const bf16x8*>(Wo_f + (size_t)((c * 8 + kt) * 64 + l) * 8);
        bf16x8 af[4];
#pragma unroll
        for (int ks = 0; ks < 4; ++ks)
            af[ks] = *reinterpret_cast<const bf16x8*>(a_f + (size_t)(((c * 16 + bi) * 4 + ks) * 64 + l) * 8);

        // Stage A: O^T fragments (swapped operands; b from LDS) -> swizzled O_lds
#pragma unroll
        for (int q = 0; q < 4; ++q) {
            f32x4 o = (f32x4){0.f, 0.f, 0.f, 0.f};
#pragma unroll
            for (int ks = 0; ks < 4; ++ks) {
                bf16x8 bfrag = *reinterpret_cast<const bf16x8*>(
                    b_lds + (size_t)(((w * 4 + q) * 4 + ks) * 64 + l) * 8);
                o = __builtin_amdgcn_mfma_f32_16x16x32_bf16(bfrag, af[ks], o, 0, 0, 0);
            }
            u16x4 pk;
            pk[0] = bf16rne(o[0]); pk[1] = bf16rne(o[1]);
            pk[2] = bf16rne(o[2]); pk[3] = bf16rne(o[3]);
            // O_lds[i = lo][col = (w*4+q)*16 + hi*4 + r], byte = i*512 + col*2
            int byte = (lo << 9) + (w * 4 + q) * 32 + (hi << 3);
            byte ^= (lo & 7) << 4;
            *reinterpret_cast<u16x4*>(reinterpret_cast<char*>(O_lds[c & 1]) + byte) = pk;
        }

        // Stage B: z += O_c @ Wo_c   (wave reads only its own O stripe: no barrier)
#pragma unroll
        for (int jj = 0; jj < 2; ++jj) {
            int rbyte = (lo << 9) + w * 128 + jj * 64 + (hi << 4);
            rbyte ^= (lo & 7) << 4;
            bf16x8 ofrag = *reinterpret_cast<const bf16x8*>(
                reinterpret_cast<const char*>(O_lds[c & 1]) + rbyte);
#pragma unroll
            for (int kt = 0; kt < 8; ++kt)
                zacc[jj][kt] = __builtin_amdgcn_mfma_f32_16x16x32_bf16(ofrag, wof[kt], zacc[jj][kt], 0, 0, 0);
        }
    }

    // Epilogue: /n_seq + bo
#pragma unroll
    for (int jj = 0; jj < 2; ++jj) {
        int j = bj * 8 + w * 2 + jj;
#pragma unroll
        for (int kt = 0; kt < 8; ++kt) {
            int k = kt * 16 + lo;
            float bok = bo[k];
#pragma unroll
            for (int r = 0; r < 4; ++r) {
                int i = bi * 16 + hi * 4 + r;
                out[((size_t)i * NR + j) * CZ + k] = zacc[jj][kt][r] * (1.f / NS) + bok;
            }
        }
    }
}

// ---------------------------------------------------------------------------
extern "C" void kernel_launch(void* const* d_in, const int* in_sizes, int n_in,
                              void* d_out, int out_size, void* d_ws, size_t ws_size,
                              hipStream_t stream) {
    const float* m   = (const float*)d_in[0];
    const float* lnw = (const float*)d_in[1];
    const float* lnb = (const float*)d_in[2];
    const float* Wa  = (const float*)d_in[3];
    const float* ba  = (const float*)d_in[4];
    const float* Wb  = (const float*)d_in[5];
    const float* bb  = (const float*)d_in[6];
    const float* Wo  = (const float*)d_in[7];
    const float* bo  = (const float*)d_in[8];
    float* out = (float*)d_out;

    // ws layout (ushort units): a_n | b_n | a_f | b_f | Wab_f | Wo_f
    unsigned short* ws    = (unsigned short*)d_ws;
    unsigned short* a_n   = ws;
    unsigned short* b_n   = ws + 1048576;
    unsigned short* a_f   = ws + 2097152;
    unsigned short* b_f   = ws + 3145728;
    unsigned short* Wab_f = ws + 4194304;
    unsigned short* Wo_f  = ws + 4210688;
    const size_t WS_NEEDED = (size_t)(4210688 + 131072) * 2;
    if (ws_size < WS_NEEDED) return;   // diagnosable: output stays poisoned

    k_wrepack<<<72, 256, 0, stream>>>(Wa, Wb, Wo, Wab_f, Wo_f);
    k_lnproj<<<512, 256, 0, stream>>>(m, lnw, lnb, ba, bb, Wab_f, a_n, b_n);
    k_abrepack<<<1024, 256, 0, stream>>>(a_n, b_n, a_f, b_f);
    k_outer<<<512, 256, 0, stream>>>(a_f, b_f, Wo_f, bo, out);
}